// Round 3
// baseline (322.673 us; speedup 1.0000x reference)
//
#include <hip/hip_runtime.h>

#define NB 32
#define ND 64
#define NT 4096
#define NK 512
#define NGRID 1024

typedef __attribute__((ext_vector_type(8))) short short8;
typedef __attribute__((ext_vector_type(16))) float f32x16;
typedef unsigned int uint32;
typedef unsigned short ushort16_t;

#define PERM(r) ((((r) & 7) * 16) + ((r) >> 3))
#define STR 68
#define ESTR 66
// acc-domain margin: safe if > emax/2 + 2*eps_dot = ~1.6e-4 (emax = 64/512^2)
#define M2 4e-4f
#define RCAP 4

__device__ __forceinline__ ushort16_t bf16rne(float f) {
    uint32 u = __float_as_uint(f);
    return (ushort16_t)((u + 0x7FFFu + ((u >> 16) & 1u)) >> 16);
}
__device__ __forceinline__ float bf16tof(ushort16_t h) {
    return __uint_as_float(((uint32)h) << 16);
}

// ---------------------------------------------------------------------------
// prep (verified R6-R8): blocks 0..15 pack cb into MFMA A-frags (bf16 hi/lo);
// block 16: exact numpy-pairwise enorm + zero loss accumulator/counter.
// ---------------------------------------------------------------------------
__global__ void prep_kernel(const float* __restrict__ cb,
                            uint4* __restrict__ cbfrag,
                            float* __restrict__ enorm,
                            double* __restrict__ loss_acc,
                            uint32* __restrict__ counter) {
    const int bi = blockIdx.x, tid = threadIdx.x;
    if (bi < 16) {
        const int t = bi * 256 + tid;
        const int c = t >> 8, rem = t & 255, s = rem >> 6, L = rem & 63;
        const int kcode = c * 32 + (L & 31);
        const int dbase = s * 16 + ((L >> 5) << 3);
        const float* src = cb + (size_t)kcode * 64 + dbase;
        const float4 pa = *(const float4*)src;
        const float4 pb = *(const float4*)(src + 4);
        const float f[8] = {pa.x, pa.y, pa.z, pa.w, pb.x, pb.y, pb.z, pb.w};
        uint32 hw[4], lw[4];
#pragma unroll
        for (int i = 0; i < 4; ++i) {
            const ushort16_t h0 = bf16rne(f[2*i]);
            const ushort16_t h1 = bf16rne(f[2*i+1]);
            const ushort16_t l0 = bf16rne(f[2*i]   - bf16tof(h0));
            const ushort16_t l1 = bf16rne(f[2*i+1] - bf16tof(h1));
            hw[i] = (uint32)h0 | ((uint32)h1 << 16);
            lw[i] = (uint32)l0 | ((uint32)l1 << 16);
        }
        cbfrag[(size_t)((c*4+s)*2 + 0)*64 + L] = make_uint4(hw[0],hw[1],hw[2],hw[3]);
        cbfrag[(size_t)((c*4+s)*2 + 1)*64 + L] = make_uint4(lw[0],lw[1],lw[2],lw[3]);
    } else {
        if (tid == 0) { *loss_acc = 0.0; *counter = 0u; }
        for (int k = tid; k < NK; k += 256) {
            const float* e = cb + (size_t)k * ND;
            float r[8];
#pragma unroll
            for (int j = 0; j < 8; ++j) {
                float s = __fmul_rn(e[j], e[j]);
#pragma unroll
                for (int i = 1; i < 8; ++i)
                    s = __fadd_rn(s, __fmul_rn(e[8*i+j], e[8*i+j]));
                r[j] = s;
            }
            enorm[k] = __fadd_rn(__fadd_rn(__fadd_rn(r[0],r[1]), __fadd_rn(r[2],r[3])),
                                 __fadd_rn(__fadd_rn(r[4],r[5]), __fadd_rn(r[6],r[7])));
        }
    }
}

// exact dist — the R1-R8 verified bit-exact chain
__device__ __forceinline__ float exact_dist(const float* __restrict__ zrow,
                                            const float* __restrict__ cb,
                                            const float* __restrict__ enl,
                                            float zn, int k2) {
    const float4* e4 = (const float4*)(cb + (size_t)k2 * ND);
    float a = 0.0f;
#pragma unroll
    for (int w = 0; w < 16; ++w) {
        const float4 ev = e4[w];
        const float4 zv = *(const float4*)(zrow + 4 * w);
        a = __builtin_fmaf(zv.x, ev.x, a);
        a = __builtin_fmaf(zv.y, ev.y, a);
        a = __builtin_fmaf(zv.z, ev.z, a);
        a = __builtin_fmaf(zv.w, ev.w, a);
    }
    return __fsub_rn(__fadd_rn(zn, enl[k2]), __fmul_rn(2.0f, a));
}

// ---------------------------------------------------------------------------
// R12 main: R9's two-pass branchless structure, with (1) acc-domain screen
// (enorm folded into the margin: no enl ds_read/fma in the hot loops),
// (2) LDS trimmed to 39968 B -> 4 blocks/CU, exactly one dispatch round,
// (3) __launch_bounds__(256,4). Pass B rescans ALL codes vs the combined
// final threshold, so the candidate set is structurally complete (no R10
// losing-half hole). Rivals resolved with the verified exact chain.
// ---------------------------------------------------------------------------
__global__ __launch_bounds__(256, 4) void vq_main(const float* __restrict__ z,
                                                  const float* __restrict__ cb,
                                                  const uint4* __restrict__ cbfrag,
                                                  const float* __restrict__ enorm,
                                                  float* __restrict__ qout,
                                                  float* __restrict__ idxout,
                                                  double* __restrict__ loss_acc,
                                                  uint32* __restrict__ counter,
                                                  float* __restrict__ out0) {
    __shared__ __align__(16) char smem[39968];
    float*       zl   = (float*)smem;              // 128 x STR (34816 B); later ech
    float*       enl  = (float*)(smem + 34816);    // 512 f32
    float*       znl  = (float*)(smem + 36864);    // 128 f32
    ushort16_t*  cand = (ushort16_t*)(smem + 37376); // 128 x 2 x RCAP u16 = 2048 B
    int*         sfin = (int*)(smem + 39424);      // 128
    double*      sred = (double*)(smem + 39936);   // 4

    const int bi    = blockIdx.x;                  // 1024
    const int b     = bi >> 5;
    const int tbase = (bi & 31) * 128;
    const int tid   = threadIdx.x;
    const size_t zoff = (size_t)b * (ND * NT) + tbase;

    // ---- stage z (verified transpose) ----
#pragma unroll
    for (int j = 0; j < 8; ++j) {
        const int qq = j * 256 + tid;
        const int i4 = qq & 31, d = qq >> 5;
        const float4 v = *(const float4*)(z + zoff + (size_t)d * NT + i4 * 4);
        const float vv[4] = {v.x, v.y, v.z, v.w};
#pragma unroll
        for (int c = 0; c < 4; ++c) {
            const int r = i4 * 4 + c;
            zl[PERM(r) * STR + d] = vv[c];
        }
    }
    for (int k = tid; k < NK; k += 256) enl[k] = enorm[k];
    __syncthreads();

    // ---- znorm (verified numpy pairwise, tid<128) ----
    if (tid < 128) {
        const int r = tid;
        const float4* zr4 = (const float4*)&zl[PERM(r) * STR];
        float x[64];
#pragma unroll
        for (int wq = 0; wq < 16; ++wq) {
            const float4 t4 = zr4[wq];
            x[4*wq] = t4.x; x[4*wq+1] = t4.y; x[4*wq+2] = t4.z; x[4*wq+3] = t4.w;
        }
        float r8[8];
#pragma unroll
        for (int jj = 0; jj < 8; ++jj) {
            float s = __fmul_rn(x[jj], x[jj]);
#pragma unroll
            for (int ii = 1; ii < 8; ++ii)
                s = __fadd_rn(s, __fmul_rn(x[8*ii+jj], x[8*ii+jj]));
            r8[jj] = s;
        }
        znl[r] = __fadd_rn(__fadd_rn(__fadd_rn(r8[0],r8[1]), __fadd_rn(r8[2],r8[3])),
                           __fadd_rn(__fadd_rn(r8[4],r8[5]), __fadd_rn(r8[6],r8[7])));
    }

    // ---- B-frags (verified: z rows bf16 hi/lo, same slot->d rule as prep) ----
    const int L    = tid & 63;
    const int w    = tid >> 6;
    const int h    = L >> 5;
    const int rowl = w * 32 + (L & 31);
    short8 bhf[4], blf[4];
    {
        const float* zrow = &zl[PERM(rowl) * STR];
#pragma unroll
        for (int s = 0; s < 4; ++s) {
            const int d0 = s * 16 + h * 8;
            const float4 pa = *(const float4*)(zrow + d0);
            const float4 pb = *(const float4*)(zrow + d0 + 4);
            const float f[8] = {pa.x, pa.y, pa.z, pa.w, pb.x, pb.y, pb.z, pb.w};
            uint32 hw[4], lw[4];
#pragma unroll
            for (int i = 0; i < 4; ++i) {
                const ushort16_t h0 = bf16rne(f[2*i]);
                const ushort16_t h1 = bf16rne(f[2*i+1]);
                const ushort16_t l0 = bf16rne(f[2*i]   - bf16tof(h0));
                const ushort16_t l1 = bf16rne(f[2*i+1] - bf16tof(h1));
                hw[i] = (uint32)h0 | ((uint32)h1 << 16);
                lw[i] = (uint32)l0 | ((uint32)l1 << 16);
            }
            union { uint4 u; short8 s8; } uh, ul;
            uh.u = make_uint4(hw[0],hw[1],hw[2],hw[3]);
            ul.u = make_uint4(lw[0],lw[1],lw[2],lw[3]);
            bhf[s] = uh.s8; blf[s] = ul.s8;
        }
    }
    __syncthreads();

    // ---- PASS A: branchless acc-domain screen (max of a), prefetched ----
    float bmax = -__builtin_inff();
    int   bk   = 0;
    {
        uint4 buf0[8], buf1[8];
#pragma unroll
        for (int p = 0; p < 8; ++p) buf0[p] = cbfrag[(size_t)p * 64 + L];
#pragma unroll 2
        for (int c = 0; c < 16; ++c) {
            const uint4* cur = (c & 1) ? buf1 : buf0;
            uint4*       nxt = (c & 1) ? buf0 : buf1;
#pragma unroll
            for (int p = 0; p < 8; ++p)            // c=15 prefetch hits ws slack
                nxt[p] = cbfrag[(size_t)((c + 1) * 8 + p) * 64 + L];
            f32x16 acc;
#pragma unroll
            for (int r = 0; r < 16; ++r) acc[r] = 0.0f;
#pragma unroll
            for (int s = 0; s < 4; ++s) {
                union { uint4 u; short8 s8; } ah, al;
                ah.u = cur[s * 2 + 0];
                al.u = cur[s * 2 + 1];
                acc = __builtin_amdgcn_mfma_f32_32x32x16_bf16(ah.s8, bhf[s], acc, 0, 0, 0);
                acc = __builtin_amdgcn_mfma_f32_32x32x16_bf16(al.s8, bhf[s], acc, 0, 0, 0);
                acc = __builtin_amdgcn_mfma_f32_32x32x16_bf16(ah.s8, blf[s], acc, 0, 0, 0);
            }
#pragma unroll
            for (int r = 0; r < 16; ++r) {
                const int kc = c * 32 + ((r & 3) + 8 * (r >> 2) + 4 * h);
                const float a = acc[r];
                if (a > bmax) { bmax = a; bk = kc; }   // 2 cndmasks, no branch
            }
        }
    }
    // cross-half combine of screen best (lexicographic -> first occurrence)
    {
        const float ob  = __shfl_xor(bmax, 32);
        const int   obk = __shfl_xor(bk, 32);
        if (ob > bmax || (ob == bmax && obk < bk)) { bmax = ob; bk = obk; }
    }
    const float thrf = bmax - M2;

    // ---- PASS B: collect rivals vs final threshold (rare appends) ----
    int myc = 0, ovf = 0;
    ushort16_t* mylist = cand + (rowl * 2 + h) * RCAP;
    {
        uint4 buf0[8], buf1[8];
#pragma unroll
        for (int p = 0; p < 8; ++p) buf0[p] = cbfrag[(size_t)p * 64 + L];
#pragma unroll 2
        for (int c = 0; c < 16; ++c) {
            const uint4* cur = (c & 1) ? buf1 : buf0;
            uint4*       nxt = (c & 1) ? buf0 : buf1;
#pragma unroll
            for (int p = 0; p < 8; ++p)
                nxt[p] = cbfrag[(size_t)((c + 1) * 8 + p) * 64 + L];
            f32x16 acc;
#pragma unroll
            for (int r = 0; r < 16; ++r) acc[r] = 0.0f;
#pragma unroll
            for (int s = 0; s < 4; ++s) {
                union { uint4 u; short8 s8; } ah, al;
                ah.u = cur[s * 2 + 0];
                al.u = cur[s * 2 + 1];
                acc = __builtin_amdgcn_mfma_f32_32x32x16_bf16(ah.s8, bhf[s], acc, 0, 0, 0);
                acc = __builtin_amdgcn_mfma_f32_32x32x16_bf16(al.s8, bhf[s], acc, 0, 0, 0);
                acc = __builtin_amdgcn_mfma_f32_32x32x16_bf16(ah.s8, blf[s], acc, 0, 0, 0);
            }
#pragma unroll
            for (int r = 0; r < 16; ++r) {
                const int kc = c * 32 + ((r & 3) + 8 * (r >> 2) + 4 * h);
                const float a = acc[r];
                if (a >= thrf && kc != bk) {
                    if (myc < RCAP) mylist[myc++] = (ushort16_t)kc;
                    else ovf = 1;
                }
            }
        }
    }

    // ---- exact resolution (only rows with rivals; verified chain) ----
    const float* zrow = &zl[PERM(rowl) * STR];
    const float  zn   = znl[rowl];
    const int    totr = myc + __shfl_xor(myc, 32);
    const int    aovf = ovf | __shfl_xor(ovf, 32);

    int bkf;
    if (aovf) {
        // overflow fallback: full exact scan of this half's codes, asc k
        float bd = __builtin_inff(); bkf = 0x7FFFFFFF;
        for (int c = 0; c < 16; ++c)
#pragma unroll
            for (int qd = 0; qd < 4; ++qd)
#pragma unroll
                for (int i = 0; i < 4; ++i) {
                    const int k2 = c * 32 + qd * 8 + h * 4 + i;
                    const float dv = exact_dist(zrow, cb, enl, zn, k2);
                    if (dv < bd || (dv == bd && k2 < bkf)) { bd = dv; bkf = k2; }
                }
        const float obd = __shfl_xor(bd, 32);
        const int   obq = __shfl_xor(bkf, 32);
        if (obd < bd || (obd == bd && obq < bkf)) bkf = obq;
    } else if (totr > 0) {
        float bd = __builtin_inff(); bkf = 0x7FFFFFFF;
        if (((bk >> 2) & 1) == h) {       // owner half exact-dots screen best
            bd = exact_dist(zrow, cb, enl, zn, bk);
            bkf = bk;
        }
        for (int i = 0; i < myc; ++i) {
            const int k2 = mylist[i];
            const float dv = exact_dist(zrow, cb, enl, zn, k2);
            if (dv < bd || (dv == bd && k2 < bkf)) { bd = dv; bkf = k2; }
        }
        const float obd = __shfl_xor(bd, 32);
        const int   obq = __shfl_xor(bkf, 32);
        if (obd < bd || (obd == bd && obq < bkf)) bkf = obq;
    } else {
        bkf = bk;                         // no rival: screen best is proven
    }
    if (h == 0) {
        sfin[rowl] = bkf;
        idxout[(size_t)b * NT + tbase + rowl] = (float)bkf;
    }
    __syncthreads();

    // ---- staged epilogue (R8 verbatim) ----
    float* ech = zl;
#pragma unroll
    for (int j = 0; j < 8; ++j) {
        const int qq  = j * 256 + tid;
        const int row = qq >> 4, d4 = qq & 15;
        const float4 v = *(const float4*)(cb + (size_t)sfin[row] * ND + d4 * 4);
        float* dst = &ech[row * ESTR + d4 * 4];
        *(float2*)(dst)     = make_float2(v.x, v.y);
        *(float2*)(dst + 2) = make_float2(v.z, v.w);
    }
    __syncthreads();

    double lsum = 0.0;
#pragma unroll 4
    for (int j = 0; j < 32; ++j) {
        const int qq = j * 256 + tid;
        const int ir = qq & 127, d = qq >> 7;
        const float zv = z[zoff + (size_t)d * NT + ir];
        const float ev = ech[ir * ESTR + d];
        const float diff = __fsub_rn(ev, zv);              // quantized - zt
        qout[(size_t)b * (ND*NT) + (size_t)d * NT + tbase + ir] = __fadd_rn(zv, diff);
        lsum += (double)diff * (double)diff;
    }
#pragma unroll
    for (int off = 32; off > 0; off >>= 1) lsum += __shfl_down(lsum, off, 64);
    if ((tid & 63) == 0) sred[tid >> 6] = lsum;
    __syncthreads();

    if (tid == 0) {
        const double bsum = (sred[0] + sred[1]) + (sred[2] + sred[3]);
        atomicAdd(loss_acc, bsum);
        __threadfence();
        const uint32 old = atomicAdd(counter, 1u);
        if (old == (uint32)(NGRID - 1)) {
            __threadfence();
            const double tot = *(volatile double*)loss_acc;
            const double m = tot / (double)((size_t)NB * NT * ND);
            out0[0] = (float)(1.25 * m);   // codebook + 0.25*commitment
        }
    }
}

extern "C" void kernel_launch(void* const* d_in, const int* in_sizes, int n_in,
                              void* d_out, int out_size, void* d_ws, size_t ws_size,
                              hipStream_t stream) {
    const float* z  = (const float*)d_in[0];
    const float* cb = (const float*)d_in[1];

    float* out      = (float*)d_out;
    float* loss_out = out;                                  // 1 elem
    float* qout     = out + 1;                              // B*D*T
    float* idxout   = out + 1 + (size_t)NB * ND * NT;       // B*T

    // cbfrag 131072 B + 8192 B slack (c=15 prefetch overrun target, unused data)
    uint4*  cbfrag   = (uint4*)d_ws;
    float*  enorm    = (float*)((char*)d_ws + 139264);      // 2048 B
    double* loss_acc = (double*)((char*)d_ws + 141312);     // 8 B
    uint32* counter  = (uint32*)((char*)d_ws + 141320);     // 4 B

    prep_kernel<<<17, 256, 0, stream>>>(cb, cbfrag, enorm, loss_acc, counter);
    vq_main<<<NGRID, 256, 0, stream>>>(z, cb, cbfrag, enorm, qout, idxout,
                                       loss_acc, counter, loss_out);
}

// Round 4
// 228.030 us; speedup vs baseline: 1.4150x; 1.4150x over previous
//
#include <hip/hip_runtime.h>

#define NB 32
#define ND 64
#define NT 4096
#define NK 512
#define NGRID 1024

typedef __attribute__((ext_vector_type(8))) short short8;
typedef __attribute__((ext_vector_type(16))) float f32x16;
typedef unsigned int uint32;
typedef unsigned short ushort16_t;

#define PERM(r) ((((r) & 7) * 16) + ((r) >> 3))
#define STR 68
#define ESTR 66
// acc-domain margin: safe if > emax/2 + 2*eps_dot = ~1.6e-4 (emax = 64/512^2)
#define M2 4e-4f
#define RCAP 4

__device__ __forceinline__ ushort16_t bf16rne(float f) {
    uint32 u = __float_as_uint(f);
    return (ushort16_t)((u + 0x7FFFu + ((u >> 16) & 1u)) >> 16);
}
__device__ __forceinline__ float bf16tof(ushort16_t h) {
    return __uint_as_float(((uint32)h) << 16);
}

// ---------------------------------------------------------------------------
// prep (verified R6-R8): blocks 0..15 pack cb into MFMA A-frags (bf16 hi/lo);
// block 16: exact numpy-pairwise enorm + zero loss accumulator/counter.
// ---------------------------------------------------------------------------
__global__ void prep_kernel(const float* __restrict__ cb,
                            uint4* __restrict__ cbfrag,
                            float* __restrict__ enorm,
                            double* __restrict__ loss_acc,
                            uint32* __restrict__ counter) {
    const int bi = blockIdx.x, tid = threadIdx.x;
    if (bi < 16) {
        const int t = bi * 256 + tid;
        const int c = t >> 8, rem = t & 255, s = rem >> 6, L = rem & 63;
        const int kcode = c * 32 + (L & 31);
        const int dbase = s * 16 + ((L >> 5) << 3);
        const float* src = cb + (size_t)kcode * 64 + dbase;
        const float4 pa = *(const float4*)src;
        const float4 pb = *(const float4*)(src + 4);
        const float f[8] = {pa.x, pa.y, pa.z, pa.w, pb.x, pb.y, pb.z, pb.w};
        uint32 hw[4], lw[4];
#pragma unroll
        for (int i = 0; i < 4; ++i) {
            const ushort16_t h0 = bf16rne(f[2*i]);
            const ushort16_t h1 = bf16rne(f[2*i+1]);
            const ushort16_t l0 = bf16rne(f[2*i]   - bf16tof(h0));
            const ushort16_t l1 = bf16rne(f[2*i+1] - bf16tof(h1));
            hw[i] = (uint32)h0 | ((uint32)h1 << 16);
            lw[i] = (uint32)l0 | ((uint32)l1 << 16);
        }
        cbfrag[(size_t)((c*4+s)*2 + 0)*64 + L] = make_uint4(hw[0],hw[1],hw[2],hw[3]);
        cbfrag[(size_t)((c*4+s)*2 + 1)*64 + L] = make_uint4(lw[0],lw[1],lw[2],lw[3]);
    } else {
        if (tid == 0) { *loss_acc = 0.0; *counter = 0u; }
        for (int k = tid; k < NK; k += 256) {
            const float* e = cb + (size_t)k * ND;
            float r[8];
#pragma unroll
            for (int j = 0; j < 8; ++j) {
                float s = __fmul_rn(e[j], e[j]);
#pragma unroll
                for (int i = 1; i < 8; ++i)
                    s = __fadd_rn(s, __fmul_rn(e[8*i+j], e[8*i+j]));
                r[j] = s;
            }
            enorm[k] = __fadd_rn(__fadd_rn(__fadd_rn(r[0],r[1]), __fadd_rn(r[2],r[3])),
                                 __fadd_rn(__fadd_rn(r[4],r[5]), __fadd_rn(r[6],r[7])));
        }
    }
}

// exact dist — the R1-R8 verified bit-exact chain
__device__ __forceinline__ float exact_dist(const float* __restrict__ zrow,
                                            const float* __restrict__ cb,
                                            const float* __restrict__ enl,
                                            float zn, int k2) {
    const float4* e4 = (const float4*)(cb + (size_t)k2 * ND);
    float a = 0.0f;
#pragma unroll
    for (int w = 0; w < 16; ++w) {
        const float4 ev = e4[w];
        const float4 zv = *(const float4*)(zrow + 4 * w);
        a = __builtin_fmaf(zv.x, ev.x, a);
        a = __builtin_fmaf(zv.y, ev.y, a);
        a = __builtin_fmaf(zv.z, ev.z, a);
        a = __builtin_fmaf(zv.w, ev.w, a);
    }
    return __fsub_rn(__fadd_rn(zn, enl[k2]), __fmul_rn(2.0f, a));
}

// ---------------------------------------------------------------------------
// R13 main: R12's two-pass acc-domain screen, but back to
// __launch_bounds__(256,3). R11/R12 evidence: the (256,4) bound squeezed
// the allocator to 64 VGPR, spilling the 16xuint4 prefetch double-buffer
// to scratch (FETCH +20MB, MfmaUtil halved). At the natural ~84 VGPR
// (<=128), HW already allows 16 waves/CU; with LDS trimmed to 40448 B,
// 4 blocks/CU fit WITHOUT the register cap. One dispatch round, no tail.
// ---------------------------------------------------------------------------
__global__ __launch_bounds__(256, 3) void vq_main(const float* __restrict__ z,
                                                  const float* __restrict__ cb,
                                                  const uint4* __restrict__ cbfrag,
                                                  const float* __restrict__ enorm,
                                                  float* __restrict__ qout,
                                                  float* __restrict__ idxout,
                                                  double* __restrict__ loss_acc,
                                                  uint32* __restrict__ counter,
                                                  float* __restrict__ out0) {
    __shared__ __align__(16) char smem[39968];
    float*       zl   = (float*)smem;              // 128 x STR (34816 B); later ech
    float*       enl  = (float*)(smem + 34816);    // 512 f32
    float*       znl  = (float*)(smem + 36864);    // 128 f32
    ushort16_t*  cand = (ushort16_t*)(smem + 37376); // 128 x 2 x RCAP u16 = 2048 B
    int*         sfin = (int*)(smem + 39424);      // 128
    double*      sred = (double*)(smem + 39936);   // 4

    const int bi    = blockIdx.x;                  // 1024
    const int b     = bi >> 5;
    const int tbase = (bi & 31) * 128;
    const int tid   = threadIdx.x;
    const size_t zoff = (size_t)b * (ND * NT) + tbase;

    // ---- stage z (verified transpose) ----
#pragma unroll
    for (int j = 0; j < 8; ++j) {
        const int qq = j * 256 + tid;
        const int i4 = qq & 31, d = qq >> 5;
        const float4 v = *(const float4*)(z + zoff + (size_t)d * NT + i4 * 4);
        const float vv[4] = {v.x, v.y, v.z, v.w};
#pragma unroll
        for (int c = 0; c < 4; ++c) {
            const int r = i4 * 4 + c;
            zl[PERM(r) * STR + d] = vv[c];
        }
    }
    for (int k = tid; k < NK; k += 256) enl[k] = enorm[k];
    __syncthreads();

    // ---- znorm (verified numpy pairwise, tid<128) ----
    if (tid < 128) {
        const int r = tid;
        const float4* zr4 = (const float4*)&zl[PERM(r) * STR];
        float x[64];
#pragma unroll
        for (int wq = 0; wq < 16; ++wq) {
            const float4 t4 = zr4[wq];
            x[4*wq] = t4.x; x[4*wq+1] = t4.y; x[4*wq+2] = t4.z; x[4*wq+3] = t4.w;
        }
        float r8[8];
#pragma unroll
        for (int jj = 0; jj < 8; ++jj) {
            float s = __fmul_rn(x[jj], x[jj]);
#pragma unroll
            for (int ii = 1; ii < 8; ++ii)
                s = __fadd_rn(s, __fmul_rn(x[8*ii+jj], x[8*ii+jj]));
            r8[jj] = s;
        }
        znl[r] = __fadd_rn(__fadd_rn(__fadd_rn(r8[0],r8[1]), __fadd_rn(r8[2],r8[3])),
                           __fadd_rn(__fadd_rn(r8[4],r8[5]), __fadd_rn(r8[6],r8[7])));
    }

    // ---- B-frags (verified: z rows bf16 hi/lo, same slot->d rule as prep) ----
    const int L    = tid & 63;
    const int w    = tid >> 6;
    const int h    = L >> 5;
    const int rowl = w * 32 + (L & 31);
    short8 bhf[4], blf[4];
    {
        const float* zrow = &zl[PERM(rowl) * STR];
#pragma unroll
        for (int s = 0; s < 4; ++s) {
            const int d0 = s * 16 + h * 8;
            const float4 pa = *(const float4*)(zrow + d0);
            const float4 pb = *(const float4*)(zrow + d0 + 4);
            const float f[8] = {pa.x, pa.y, pa.z, pa.w, pb.x, pb.y, pb.z, pb.w};
            uint32 hw[4], lw[4];
#pragma unroll
            for (int i = 0; i < 4; ++i) {
                const ushort16_t h0 = bf16rne(f[2*i]);
                const ushort16_t h1 = bf16rne(f[2*i+1]);
                const ushort16_t l0 = bf16rne(f[2*i]   - bf16tof(h0));
                const ushort16_t l1 = bf16rne(f[2*i+1] - bf16tof(h1));
                hw[i] = (uint32)h0 | ((uint32)h1 << 16);
                lw[i] = (uint32)l0 | ((uint32)l1 << 16);
            }
            union { uint4 u; short8 s8; } uh, ul;
            uh.u = make_uint4(hw[0],hw[1],hw[2],hw[3]);
            ul.u = make_uint4(lw[0],lw[1],lw[2],lw[3]);
            bhf[s] = uh.s8; blf[s] = ul.s8;
        }
    }
    __syncthreads();

    // ---- PASS A: branchless acc-domain screen (max of a), prefetched ----
    float bmax = -__builtin_inff();
    int   bk   = 0;
    {
        uint4 buf0[8], buf1[8];
#pragma unroll
        for (int p = 0; p < 8; ++p) buf0[p] = cbfrag[(size_t)p * 64 + L];
#pragma unroll 2
        for (int c = 0; c < 16; ++c) {
            const uint4* cur = (c & 1) ? buf1 : buf0;
            uint4*       nxt = (c & 1) ? buf0 : buf1;
#pragma unroll
            for (int p = 0; p < 8; ++p)            // c=15 prefetch hits ws slack
                nxt[p] = cbfrag[(size_t)((c + 1) * 8 + p) * 64 + L];
            f32x16 acc;
#pragma unroll
            for (int r = 0; r < 16; ++r) acc[r] = 0.0f;
#pragma unroll
            for (int s = 0; s < 4; ++s) {
                union { uint4 u; short8 s8; } ah, al;
                ah.u = cur[s * 2 + 0];
                al.u = cur[s * 2 + 1];
                acc = __builtin_amdgcn_mfma_f32_32x32x16_bf16(ah.s8, bhf[s], acc, 0, 0, 0);
                acc = __builtin_amdgcn_mfma_f32_32x32x16_bf16(al.s8, bhf[s], acc, 0, 0, 0);
                acc = __builtin_amdgcn_mfma_f32_32x32x16_bf16(ah.s8, blf[s], acc, 0, 0, 0);
            }
#pragma unroll
            for (int r = 0; r < 16; ++r) {
                const int kc = c * 32 + ((r & 3) + 8 * (r >> 2) + 4 * h);
                const float a = acc[r];
                if (a > bmax) { bmax = a; bk = kc; }   // 2 cndmasks, no branch
            }
        }
    }
    // cross-half combine of screen best (lexicographic -> first occurrence)
    {
        const float ob  = __shfl_xor(bmax, 32);
        const int   obk = __shfl_xor(bk, 32);
        if (ob > bmax || (ob == bmax && obk < bk)) { bmax = ob; bk = obk; }
    }
    const float thrf = bmax - M2;

    // ---- PASS B: collect rivals vs final threshold (rare appends) ----
    int myc = 0, ovf = 0;
    ushort16_t* mylist = cand + (rowl * 2 + h) * RCAP;
    {
        uint4 buf0[8], buf1[8];
#pragma unroll
        for (int p = 0; p < 8; ++p) buf0[p] = cbfrag[(size_t)p * 64 + L];
#pragma unroll 2
        for (int c = 0; c < 16; ++c) {
            const uint4* cur = (c & 1) ? buf1 : buf0;
            uint4*       nxt = (c & 1) ? buf0 : buf1;
#pragma unroll
            for (int p = 0; p < 8; ++p)
                nxt[p] = cbfrag[(size_t)((c + 1) * 8 + p) * 64 + L];
            f32x16 acc;
#pragma unroll
            for (int r = 0; r < 16; ++r) acc[r] = 0.0f;
#pragma unroll
            for (int s = 0; s < 4; ++s) {
                union { uint4 u; short8 s8; } ah, al;
                ah.u = cur[s * 2 + 0];
                al.u = cur[s * 2 + 1];
                acc = __builtin_amdgcn_mfma_f32_32x32x16_bf16(ah.s8, bhf[s], acc, 0, 0, 0);
                acc = __builtin_amdgcn_mfma_f32_32x32x16_bf16(al.s8, bhf[s], acc, 0, 0, 0);
                acc = __builtin_amdgcn_mfma_f32_32x32x16_bf16(ah.s8, blf[s], acc, 0, 0, 0);
            }
#pragma unroll
            for (int r = 0; r < 16; ++r) {
                const int kc = c * 32 + ((r & 3) + 8 * (r >> 2) + 4 * h);
                const float a = acc[r];
                if (a >= thrf && kc != bk) {
                    if (myc < RCAP) mylist[myc++] = (ushort16_t)kc;
                    else ovf = 1;
                }
            }
        }
    }

    // ---- exact resolution (only rows with rivals; verified chain) ----
    const float* zrow = &zl[PERM(rowl) * STR];
    const float  zn   = znl[rowl];
    const int    totr = myc + __shfl_xor(myc, 32);
    const int    aovf = ovf | __shfl_xor(ovf, 32);

    int bkf;
    if (aovf) {
        // overflow fallback: full exact scan of this half's codes, asc k
        float bd = __builtin_inff(); bkf = 0x7FFFFFFF;
        for (int c = 0; c < 16; ++c)
#pragma unroll
            for (int qd = 0; qd < 4; ++qd)
#pragma unroll
                for (int i = 0; i < 4; ++i) {
                    const int k2 = c * 32 + qd * 8 + h * 4 + i;
                    const float dv = exact_dist(zrow, cb, enl, zn, k2);
                    if (dv < bd || (dv == bd && k2 < bkf)) { bd = dv; bkf = k2; }
                }
        const float obd = __shfl_xor(bd, 32);
        const int   obq = __shfl_xor(bkf, 32);
        if (obd < bd || (obd == bd && obq < bkf)) bkf = obq;
    } else if (totr > 0) {
        float bd = __builtin_inff(); bkf = 0x7FFFFFFF;
        if (((bk >> 2) & 1) == h) {       // owner half exact-dots screen best
            bd = exact_dist(zrow, cb, enl, zn, bk);
            bkf = bk;
        }
        for (int i = 0; i < myc; ++i) {
            const int k2 = mylist[i];
            const float dv = exact_dist(zrow, cb, enl, zn, k2);
            if (dv < bd || (dv == bd && k2 < bkf)) { bd = dv; bkf = k2; }
        }
        const float obd = __shfl_xor(bd, 32);
        const int   obq = __shfl_xor(bkf, 32);
        if (obd < bd || (obd == bd && obq < bkf)) bkf = obq;
    } else {
        bkf = bk;                         // no rival: screen best is proven
    }
    if (h == 0) {
        sfin[rowl] = bkf;
        idxout[(size_t)b * NT + tbase + rowl] = (float)bkf;
    }
    __syncthreads();

    // ---- staged epilogue (R8 verbatim) ----
    float* ech = zl;
#pragma unroll
    for (int j = 0; j < 8; ++j) {
        const int qq  = j * 256 + tid;
        const int row = qq >> 4, d4 = qq & 15;
        const float4 v = *(const float4*)(cb + (size_t)sfin[row] * ND + d4 * 4);
        float* dst = &ech[row * ESTR + d4 * 4];
        *(float2*)(dst)     = make_float2(v.x, v.y);
        *(float2*)(dst + 2) = make_float2(v.z, v.w);
    }
    __syncthreads();

    double lsum = 0.0;
#pragma unroll 4
    for (int j = 0; j < 32; ++j) {
        const int qq = j * 256 + tid;
        const int ir = qq & 127, d = qq >> 7;
        const float zv = z[zoff + (size_t)d * NT + ir];
        const float ev = ech[ir * ESTR + d];
        const float diff = __fsub_rn(ev, zv);              // quantized - zt
        qout[(size_t)b * (ND*NT) + (size_t)d * NT + tbase + ir] = __fadd_rn(zv, diff);
        lsum += (double)diff * (double)diff;
    }
#pragma unroll
    for (int off = 32; off > 0; off >>= 1) lsum += __shfl_down(lsum, off, 64);
    if ((tid & 63) == 0) sred[tid >> 6] = lsum;
    __syncthreads();

    if (tid == 0) {
        const double bsum = (sred[0] + sred[1]) + (sred[2] + sred[3]);
        atomicAdd(loss_acc, bsum);
        __threadfence();
        const uint32 old = atomicAdd(counter, 1u);
        if (old == (uint32)(NGRID - 1)) {
            __threadfence();
            const double tot = *(volatile double*)loss_acc;
            const double m = tot / (double)((size_t)NB * NT * ND);
            out0[0] = (float)(1.25 * m);   // codebook + 0.25*commitment
        }
    }
}

extern "C" void kernel_launch(void* const* d_in, const int* in_sizes, int n_in,
                              void* d_out, int out_size, void* d_ws, size_t ws_size,
                              hipStream_t stream) {
    const float* z  = (const float*)d_in[0];
    const float* cb = (const float*)d_in[1];

    float* out      = (float*)d_out;
    float* loss_out = out;                                  // 1 elem
    float* qout     = out + 1;                              // B*D*T
    float* idxout   = out + 1 + (size_t)NB * ND * NT;       // B*T

    // cbfrag 131072 B + 8192 B slack (c=15 prefetch overrun target, unused data)
    uint4*  cbfrag   = (uint4*)d_ws;
    float*  enorm    = (float*)((char*)d_ws + 139264);      // 2048 B
    double* loss_acc = (double*)((char*)d_ws + 141312);     // 8 B
    uint32* counter  = (uint32*)((char*)d_ws + 141320);     // 4 B

    prep_kernel<<<17, 256, 0, stream>>>(cb, cbfrag, enorm, loss_acc, counter);
    vq_main<<<NGRID, 256, 0, stream>>>(z, cb, cbfrag, enorm, qout, idxout,
                                       loss_acc, counter, loss_out);
}

// Round 5
// 227.495 us; speedup vs baseline: 1.4184x; 1.0024x over previous
//
#include <hip/hip_runtime.h>

#define NB 32
#define ND 64
#define NT 4096
#define NK 512
#define NGRID 1024

typedef __attribute__((ext_vector_type(8))) short short8;
typedef __attribute__((ext_vector_type(16))) float f32x16;
typedef unsigned int uint32;
typedef unsigned short ushort16_t;

#define PERM(r) ((((r) & 7) * 16) + ((r) >> 3))
#define STR 68
#define ESTR 66
// acc-domain margin: safe if > emax/2 + 2*eps_dot = ~1.6e-4 (emax = 64/512^2)
#define M2 4e-4f
#define RCAP 4

__device__ __forceinline__ ushort16_t bf16rne(float f) {
    uint32 u = __float_as_uint(f);
    return (ushort16_t)((u + 0x7FFFu + ((u >> 16) & 1u)) >> 16);
}
__device__ __forceinline__ float bf16tof(ushort16_t h) {
    return __uint_as_float(((uint32)h) << 16);
}

// ---------------------------------------------------------------------------
// prep (verified R6-R8): blocks 0..15 pack cb into MFMA A-frags (bf16 hi/lo);
// block 16: exact numpy-pairwise enorm + zero loss accumulator/counter.
// ---------------------------------------------------------------------------
__global__ void prep_kernel(const float* __restrict__ cb,
                            uint4* __restrict__ cbfrag,
                            float* __restrict__ enorm,
                            double* __restrict__ loss_acc,
                            uint32* __restrict__ counter) {
    const int bi = blockIdx.x, tid = threadIdx.x;
    if (bi < 16) {
        const int t = bi * 256 + tid;
        const int c = t >> 8, rem = t & 255, s = rem >> 6, L = rem & 63;
        const int kcode = c * 32 + (L & 31);
        const int dbase = s * 16 + ((L >> 5) << 3);
        const float* src = cb + (size_t)kcode * 64 + dbase;
        const float4 pa = *(const float4*)src;
        const float4 pb = *(const float4*)(src + 4);
        const float f[8] = {pa.x, pa.y, pa.z, pa.w, pb.x, pb.y, pb.z, pb.w};
        uint32 hw[4], lw[4];
#pragma unroll
        for (int i = 0; i < 4; ++i) {
            const ushort16_t h0 = bf16rne(f[2*i]);
            const ushort16_t h1 = bf16rne(f[2*i+1]);
            const ushort16_t l0 = bf16rne(f[2*i]   - bf16tof(h0));
            const ushort16_t l1 = bf16rne(f[2*i+1] - bf16tof(h1));
            hw[i] = (uint32)h0 | ((uint32)h1 << 16);
            lw[i] = (uint32)l0 | ((uint32)l1 << 16);
        }
        cbfrag[(size_t)((c*4+s)*2 + 0)*64 + L] = make_uint4(hw[0],hw[1],hw[2],hw[3]);
        cbfrag[(size_t)((c*4+s)*2 + 1)*64 + L] = make_uint4(lw[0],lw[1],lw[2],lw[3]);
    } else {
        if (tid == 0) { *loss_acc = 0.0; *counter = 0u; }
        for (int k = tid; k < NK; k += 256) {
            const float* e = cb + (size_t)k * ND;
            float r[8];
#pragma unroll
            for (int j = 0; j < 8; ++j) {
                float s = __fmul_rn(e[j], e[j]);
#pragma unroll
                for (int i = 1; i < 8; ++i)
                    s = __fadd_rn(s, __fmul_rn(e[8*i+j], e[8*i+j]));
                r[j] = s;
            }
            enorm[k] = __fadd_rn(__fadd_rn(__fadd_rn(r[0],r[1]), __fadd_rn(r[2],r[3])),
                                 __fadd_rn(__fadd_rn(r[4],r[5]), __fadd_rn(r[6],r[7])));
        }
    }
}

// exact dist — the R1-R8 verified bit-exact chain
__device__ __forceinline__ float exact_dist(const float* __restrict__ zrow,
                                            const float* __restrict__ cb,
                                            const float* __restrict__ enl,
                                            float zn, int k2) {
    const float4* e4 = (const float4*)(cb + (size_t)k2 * ND);
    float a = 0.0f;
#pragma unroll
    for (int w = 0; w < 16; ++w) {
        const float4 ev = e4[w];
        const float4 zv = *(const float4*)(zrow + 4 * w);
        a = __builtin_fmaf(zv.x, ev.x, a);
        a = __builtin_fmaf(zv.y, ev.y, a);
        a = __builtin_fmaf(zv.z, ev.z, a);
        a = __builtin_fmaf(zv.w, ev.w, a);
    }
    return __fsub_rn(__fadd_rn(zn, enl[k2]), __fmul_rn(2.0f, a));
}

// ---------------------------------------------------------------------------
// R14 main: R13's two-pass acc-domain screen + resolution VERBATIM, but the
// A-fragments are LDS-STAGED once per block (double-buffered, reg-staged
// 2 loads + 2 ds_write_b128 per wave per chunk, 1 barrier per chunk) and
// read by all 4 waves via conflict-free ds_read_b128. This cuts the
// dominant VMEM stream 4x (all waves previously loaded identical A-frags:
// 1 MB/block -> 256 KB/block) and frees ~64 VGPR of register double-buffer.
// LDS 56352 B -> 2 blocks/CU (screen hides latency via the LDS pipeline,
// not cross-wave TLP).
// ---------------------------------------------------------------------------
__global__ __launch_bounds__(256, 3) void vq_main(const float* __restrict__ z,
                                                  const float* __restrict__ cb,
                                                  const uint4* __restrict__ cbfrag,
                                                  const float* __restrict__ enorm,
                                                  float* __restrict__ qout,
                                                  float* __restrict__ idxout,
                                                  double* __restrict__ loss_acc,
                                                  uint32* __restrict__ counter,
                                                  float* __restrict__ out0) {
    __shared__ __align__(16) char smem[56352];
    float*       zl   = (float*)smem;              // 128 x STR (34816 B); later ech
    float*       enl  = (float*)(smem + 34816);    // 512 f32
    float*       znl  = (float*)(smem + 36864);    // 128 f32
    ushort16_t*  cand = (ushort16_t*)(smem + 37376); // 128 x 2 x RCAP u16 = 2048 B
    int*         sfin = (int*)(smem + 39424);      // 128
    double*      sred = (double*)(smem + 39936);   // 4 (ends 39968)
    uint4*       cbs  = (uint4*)(smem + 39968);    // 2 x 512 uint4 = 16384 B

    const int bi    = blockIdx.x;                  // 1024
    const int b     = bi >> 5;
    const int tbase = (bi & 31) * 128;
    const int tid   = threadIdx.x;
    const size_t zoff = (size_t)b * (ND * NT) + tbase;

    // ---- stage z (verified transpose) ----
#pragma unroll
    for (int j = 0; j < 8; ++j) {
        const int qq = j * 256 + tid;
        const int i4 = qq & 31, d = qq >> 5;
        const float4 v = *(const float4*)(z + zoff + (size_t)d * NT + i4 * 4);
        const float vv[4] = {v.x, v.y, v.z, v.w};
#pragma unroll
        for (int c = 0; c < 4; ++c) {
            const int r = i4 * 4 + c;
            zl[PERM(r) * STR + d] = vv[c];
        }
    }
    for (int k = tid; k < NK; k += 256) enl[k] = enorm[k];
    __syncthreads();

    // ---- znorm (verified numpy pairwise, tid<128) ----
    if (tid < 128) {
        const int r = tid;
        const float4* zr4 = (const float4*)&zl[PERM(r) * STR];
        float x[64];
#pragma unroll
        for (int wq = 0; wq < 16; ++wq) {
            const float4 t4 = zr4[wq];
            x[4*wq] = t4.x; x[4*wq+1] = t4.y; x[4*wq+2] = t4.z; x[4*wq+3] = t4.w;
        }
        float r8[8];
#pragma unroll
        for (int jj = 0; jj < 8; ++jj) {
            float s = __fmul_rn(x[jj], x[jj]);
#pragma unroll
            for (int ii = 1; ii < 8; ++ii)
                s = __fadd_rn(s, __fmul_rn(x[8*ii+jj], x[8*ii+jj]));
            r8[jj] = s;
        }
        znl[r] = __fadd_rn(__fadd_rn(__fadd_rn(r8[0],r8[1]), __fadd_rn(r8[2],r8[3])),
                           __fadd_rn(__fadd_rn(r8[4],r8[5]), __fadd_rn(r8[6],r8[7])));
    }

    // ---- B-frags (verified: z rows bf16 hi/lo, same slot->d rule as prep) ----
    const int L    = tid & 63;
    const int w    = tid >> 6;
    const int h    = L >> 5;
    const int rowl = w * 32 + (L & 31);
    short8 bhf[4], blf[4];
    {
        const float* zrow = &zl[PERM(rowl) * STR];
#pragma unroll
        for (int s = 0; s < 4; ++s) {
            const int d0 = s * 16 + h * 8;
            const float4 pa = *(const float4*)(zrow + d0);
            const float4 pb = *(const float4*)(zrow + d0 + 4);
            const float f[8] = {pa.x, pa.y, pa.z, pa.w, pb.x, pb.y, pb.z, pb.w};
            uint32 hw[4], lw[4];
#pragma unroll
            for (int i = 0; i < 4; ++i) {
                const ushort16_t h0 = bf16rne(f[2*i]);
                const ushort16_t h1 = bf16rne(f[2*i+1]);
                const ushort16_t l0 = bf16rne(f[2*i]   - bf16tof(h0));
                const ushort16_t l1 = bf16rne(f[2*i+1] - bf16tof(h1));
                hw[i] = (uint32)h0 | ((uint32)h1 << 16);
                lw[i] = (uint32)l0 | ((uint32)l1 << 16);
            }
            union { uint4 u; short8 s8; } uh, ul;
            uh.u = make_uint4(hw[0],hw[1],hw[2],hw[3]);
            ul.u = make_uint4(lw[0],lw[1],lw[2],lw[3]);
            bhf[s] = uh.s8; blf[s] = ul.s8;
        }
    }
    __syncthreads();

    // per-wave staging pieces: wave w owns chunk pieces p = 2w, 2w+1
    const int p0 = w * 2, p1 = w * 2 + 1;

    // ---- PASS A: branchless acc-domain screen, LDS-staged A-frags ----
    float bmax = -__builtin_inff();
    int   bk   = 0;
    {
        // prologue: stage chunk 0 into cbs[0]
        const uint4 t0 = cbfrag[(size_t)(p0 * 64) + L];
        const uint4 t1 = cbfrag[(size_t)(p1 * 64) + L];
        cbs[p0 * 64 + L] = t0;
        cbs[p1 * 64 + L] = t1;
        __syncthreads();
#pragma unroll 2
        for (int c = 0; c < 16; ++c) {
            // issue next-chunk loads early (c=15 reads ws slack, unused)
            const uint4 n0 = cbfrag[(size_t)(((c + 1) * 8 + p0) * 64) + L];
            const uint4 n1 = cbfrag[(size_t)(((c + 1) * 8 + p1) * 64) + L];
            const uint4* S = cbs + (c & 1) * 512;
            f32x16 acc;
#pragma unroll
            for (int r = 0; r < 16; ++r) acc[r] = 0.0f;
#pragma unroll
            for (int s = 0; s < 4; ++s) {
                union { uint4 u; short8 s8; } ah, al;
                ah.u = S[(s * 2 + 0) * 64 + L];            // ds_read_b128
                al.u = S[(s * 2 + 1) * 64 + L];
                acc = __builtin_amdgcn_mfma_f32_32x32x16_bf16(ah.s8, bhf[s], acc, 0, 0, 0);
                acc = __builtin_amdgcn_mfma_f32_32x32x16_bf16(al.s8, bhf[s], acc, 0, 0, 0);
                acc = __builtin_amdgcn_mfma_f32_32x32x16_bf16(ah.s8, blf[s], acc, 0, 0, 0);
            }
#pragma unroll
            for (int r = 0; r < 16; ++r) {
                const int kc = c * 32 + ((r & 3) + 8 * (r >> 2) + 4 * h);
                const float a = acc[r];
                if (a > bmax) { bmax = a; bk = kc; }   // 2 cndmasks, no branch
            }
            // stage next chunk into the other buffer
            uint4* D = cbs + ((c & 1) ^ 1) * 512;
            D[p0 * 64 + L] = n0;
            D[p1 * 64 + L] = n1;
            __syncthreads();
        }
    }
    // cross-half combine of screen best (lexicographic -> first occurrence)
    {
        const float ob  = __shfl_xor(bmax, 32);
        const int   obk = __shfl_xor(bk, 32);
        if (ob > bmax || (ob == bmax && obk < bk)) { bmax = ob; bk = obk; }
    }
    const float thrf = bmax - M2;

    // ---- PASS B: collect rivals vs final threshold (rare appends) ----
    int myc = 0, ovf = 0;
    ushort16_t* mylist = cand + (rowl * 2 + h) * RCAP;
    {
        // prologue: re-stage chunk 0 (cbs holds junk from pass A tail)
        const uint4 t0 = cbfrag[(size_t)(p0 * 64) + L];
        const uint4 t1 = cbfrag[(size_t)(p1 * 64) + L];
        cbs[p0 * 64 + L] = t0;
        cbs[p1 * 64 + L] = t1;
        __syncthreads();
#pragma unroll 2
        for (int c = 0; c < 16; ++c) {
            const uint4 n0 = cbfrag[(size_t)(((c + 1) * 8 + p0) * 64) + L];
            const uint4 n1 = cbfrag[(size_t)(((c + 1) * 8 + p1) * 64) + L];
            const uint4* S = cbs + (c & 1) * 512;
            f32x16 acc;
#pragma unroll
            for (int r = 0; r < 16; ++r) acc[r] = 0.0f;
#pragma unroll
            for (int s = 0; s < 4; ++s) {
                union { uint4 u; short8 s8; } ah, al;
                ah.u = S[(s * 2 + 0) * 64 + L];
                al.u = S[(s * 2 + 1) * 64 + L];
                acc = __builtin_amdgcn_mfma_f32_32x32x16_bf16(ah.s8, bhf[s], acc, 0, 0, 0);
                acc = __builtin_amdgcn_mfma_f32_32x32x16_bf16(al.s8, bhf[s], acc, 0, 0, 0);
                acc = __builtin_amdgcn_mfma_f32_32x32x16_bf16(ah.s8, blf[s], acc, 0, 0, 0);
            }
#pragma unroll
            for (int r = 0; r < 16; ++r) {
                const int kc = c * 32 + ((r & 3) + 8 * (r >> 2) + 4 * h);
                const float a = acc[r];
                if (a >= thrf && kc != bk) {
                    if (myc < RCAP) mylist[myc++] = (ushort16_t)kc;
                    else ovf = 1;
                }
            }
            uint4* D = cbs + ((c & 1) ^ 1) * 512;
            D[p0 * 64 + L] = n0;
            D[p1 * 64 + L] = n1;
            __syncthreads();
        }
    }

    // ---- exact resolution (only rows with rivals; verified chain) ----
    const float* zrow = &zl[PERM(rowl) * STR];
    const float  zn   = znl[rowl];
    const int    totr = myc + __shfl_xor(myc, 32);
    const int    aovf = ovf | __shfl_xor(ovf, 32);

    int bkf;
    if (aovf) {
        // overflow fallback: full exact scan of this half's codes, asc k
        float bd = __builtin_inff(); bkf = 0x7FFFFFFF;
        for (int c = 0; c < 16; ++c)
#pragma unroll
            for (int qd = 0; qd < 4; ++qd)
#pragma unroll
                for (int i = 0; i < 4; ++i) {
                    const int k2 = c * 32 + qd * 8 + h * 4 + i;
                    const float dv = exact_dist(zrow, cb, enl, zn, k2);
                    if (dv < bd || (dv == bd && k2 < bkf)) { bd = dv; bkf = k2; }
                }
        const float obd = __shfl_xor(bd, 32);
        const int   obq = __shfl_xor(bkf, 32);
        if (obd < bd || (obd == bd && obq < bkf)) bkf = obq;
    } else if (totr > 0) {
        float bd = __builtin_inff(); bkf = 0x7FFFFFFF;
        if (((bk >> 2) & 1) == h) {       // owner half exact-dots screen best
            bd = exact_dist(zrow, cb, enl, zn, bk);
            bkf = bk;
        }
        for (int i = 0; i < myc; ++i) {
            const int k2 = mylist[i];
            const float dv = exact_dist(zrow, cb, enl, zn, k2);
            if (dv < bd || (dv == bd && k2 < bkf)) { bd = dv; bkf = k2; }
        }
        const float obd = __shfl_xor(bd, 32);
        const int   obq = __shfl_xor(bkf, 32);
        if (obd < bd || (obd == bd && obq < bkf)) bkf = obq;
    } else {
        bkf = bk;                         // no rival: screen best is proven
    }
    if (h == 0) {
        sfin[rowl] = bkf;
        idxout[(size_t)b * NT + tbase + rowl] = (float)bkf;
    }
    __syncthreads();

    // ---- staged epilogue (R8 verbatim) ----
    float* ech = zl;
#pragma unroll
    for (int j = 0; j < 8; ++j) {
        const int qq  = j * 256 + tid;
        const int row = qq >> 4, d4 = qq & 15;
        const float4 v = *(const float4*)(cb + (size_t)sfin[row] * ND + d4 * 4);
        float* dst = &ech[row * ESTR + d4 * 4];
        *(float2*)(dst)     = make_float2(v.x, v.y);
        *(float2*)(dst + 2) = make_float2(v.z, v.w);
    }
    __syncthreads();

    double lsum = 0.0;
#pragma unroll 4
    for (int j = 0; j < 32; ++j) {
        const int qq = j * 256 + tid;
        const int ir = qq & 127, d = qq >> 7;
        const float zv = z[zoff + (size_t)d * NT + ir];
        const float ev = ech[ir * ESTR + d];
        const float diff = __fsub_rn(ev, zv);              // quantized - zt
        qout[(size_t)b * (ND*NT) + (size_t)d * NT + tbase + ir] = __fadd_rn(zv, diff);
        lsum += (double)diff * (double)diff;
    }
#pragma unroll
    for (int off = 32; off > 0; off >>= 1) lsum += __shfl_down(lsum, off, 64);
    if ((tid & 63) == 0) sred[tid >> 6] = lsum;
    __syncthreads();

    if (tid == 0) {
        const double bsum = (sred[0] + sred[1]) + (sred[2] + sred[3]);
        atomicAdd(loss_acc, bsum);
        __threadfence();
        const uint32 old = atomicAdd(counter, 1u);
        if (old == (uint32)(NGRID - 1)) {
            __threadfence();
            const double tot = *(volatile double*)loss_acc;
            const double m = tot / (double)((size_t)NB * NT * ND);
            out0[0] = (float)(1.25 * m);   // codebook + 0.25*commitment
        }
    }
}

extern "C" void kernel_launch(void* const* d_in, const int* in_sizes, int n_in,
                              void* d_out, int out_size, void* d_ws, size_t ws_size,
                              hipStream_t stream) {
    const float* z  = (const float*)d_in[0];
    const float* cb = (const float*)d_in[1];

    float* out      = (float*)d_out;
    float* loss_out = out;                                  // 1 elem
    float* qout     = out + 1;                              // B*D*T
    float* idxout   = out + 1 + (size_t)NB * ND * NT;       // B*T

    // cbfrag 131072 B + 8192 B slack (c=15 prefetch overrun target, unused data)
    uint4*  cbfrag   = (uint4*)d_ws;
    float*  enorm    = (float*)((char*)d_ws + 139264);      // 2048 B
    double* loss_acc = (double*)((char*)d_ws + 141312);     // 8 B
    uint32* counter  = (uint32*)((char*)d_ws + 141320);     // 4 B

    prep_kernel<<<17, 256, 0, stream>>>(cb, cbfrag, enorm, loss_acc, counter);
    vq_main<<<NGRID, 256, 0, stream>>>(z, cb, cbfrag, enorm, qout, idxout,
                                       loss_acc, counter, loss_out);
}

// Round 6
// 187.435 us; speedup vs baseline: 1.7215x; 1.2137x over previous
//
#include <hip/hip_runtime.h>

#define NB 32
#define ND 64
#define NT 4096
#define NK 512
#define NGRID 1024

typedef __attribute__((ext_vector_type(8))) short short8;
typedef __attribute__((ext_vector_type(16))) float f32x16;
typedef unsigned int uint32;
typedef unsigned short ushort16_t;

#define PERM(r) ((((r) & 7) * 16) + ((r) >> 3))
#define STR 68
#define ESTR 66
// acc-domain margin: bound = emax/2 + 2*eps_dot ~= 1.56e-4 (emax = 64/512^2).
// M2 = 2.5e-4 gives 1.6x safety; packed-quantization (<=6.1e-5) only WIDENS
// collection (round-down superset) and the p3-guard (more fallbacks) - safe.
#define M2 2.5e-4f
#define RCAP 4

__device__ __forceinline__ ushort16_t bf16rne(float f) {
    uint32 u = __float_as_uint(f);
    return (ushort16_t)((u + 0x7FFFu + ((u >> 16) & 1u)) >> 16);
}
__device__ __forceinline__ float bf16tof(ushort16_t h) {
    return __uint_as_float(((uint32)h) << 16);
}

// ---------------------------------------------------------------------------
// prep (verified R6-R8): blocks 0..15 pack cb into MFMA A-frags (bf16 hi/lo);
// block 16: exact numpy-pairwise enorm + zero loss accumulator/counter.
// ---------------------------------------------------------------------------
__global__ void prep_kernel(const float* __restrict__ cb,
                            uint4* __restrict__ cbfrag,
                            float* __restrict__ enorm,
                            double* __restrict__ loss_acc,
                            uint32* __restrict__ counter) {
    const int bi = blockIdx.x, tid = threadIdx.x;
    if (bi < 16) {
        const int t = bi * 256 + tid;
        const int c = t >> 8, rem = t & 255, s = rem >> 6, L = rem & 63;
        const int kcode = c * 32 + (L & 31);
        const int dbase = s * 16 + ((L >> 5) << 3);
        const float* src = cb + (size_t)kcode * 64 + dbase;
        const float4 pa = *(const float4*)src;
        const float4 pb = *(const float4*)(src + 4);
        const float f[8] = {pa.x, pa.y, pa.z, pa.w, pb.x, pb.y, pb.z, pb.w};
        uint32 hw[4], lw[4];
#pragma unroll
        for (int i = 0; i < 4; ++i) {
            const ushort16_t h0 = bf16rne(f[2*i]);
            const ushort16_t h1 = bf16rne(f[2*i+1]);
            const ushort16_t l0 = bf16rne(f[2*i]   - bf16tof(h0));
            const ushort16_t l1 = bf16rne(f[2*i+1] - bf16tof(h1));
            hw[i] = (uint32)h0 | ((uint32)h1 << 16);
            lw[i] = (uint32)l0 | ((uint32)l1 << 16);
        }
        cbfrag[(size_t)((c*4+s)*2 + 0)*64 + L] = make_uint4(hw[0],hw[1],hw[2],hw[3]);
        cbfrag[(size_t)((c*4+s)*2 + 1)*64 + L] = make_uint4(lw[0],lw[1],lw[2],lw[3]);
    } else {
        if (tid == 0) { *loss_acc = 0.0; *counter = 0u; }
        for (int k = tid; k < NK; k += 256) {
            const float* e = cb + (size_t)k * ND;
            float r[8];
#pragma unroll
            for (int j = 0; j < 8; ++j) {
                float s = __fmul_rn(e[j], e[j]);
#pragma unroll
                for (int i = 1; i < 8; ++i)
                    s = __fadd_rn(s, __fmul_rn(e[8*i+j], e[8*i+j]));
                r[j] = s;
            }
            enorm[k] = __fadd_rn(__fadd_rn(__fadd_rn(r[0],r[1]), __fadd_rn(r[2],r[3])),
                                 __fadd_rn(__fadd_rn(r[4],r[5]), __fadd_rn(r[6],r[7])));
        }
    }
}

// exact dist — the R1-R8 verified bit-exact chain
__device__ __forceinline__ float exact_dist(const float* __restrict__ zrow,
                                            const float* __restrict__ cb,
                                            const float* __restrict__ enl,
                                            float zn, int k2) {
    const float4* e4 = (const float4*)(cb + (size_t)k2 * ND);
    float a = 0.0f;
#pragma unroll
    for (int w = 0; w < 16; ++w) {
        const float4 ev = e4[w];
        const float4 zv = *(const float4*)(zrow + 4 * w);
        a = __builtin_fmaf(zv.x, ev.x, a);
        a = __builtin_fmaf(zv.y, ev.y, a);
        a = __builtin_fmaf(zv.z, ev.z, a);
        a = __builtin_fmaf(zv.w, ev.w, a);
    }
    return __fsub_rn(__fadd_rn(zn, enl[k2]), __fmul_rn(2.0f, a));
}

// ---------------------------------------------------------------------------
// R15 main: ONE-pass screen, zero barriers in the screen. Per lane: sorted
// packed top-3 of (quantized(a+1)|k) u32 (branchless, 11 VALU/elem).
// After the cross-half max: rivals are already in registers (k2 and the
// losing half's k1 — the R11 fix is structural now). Completeness guard:
// p3 >= thrF => this wave runs a rare (~25%) conditional barrier-free
// pass-B collect (R13 list logic). Quantized value-ties force a rival =>
// exact resolution restores first-occurrence order. Exact chain, epilogue,
// loss: R13-verbatim.
// ---------------------------------------------------------------------------
__global__ __launch_bounds__(256, 3) void vq_main(const float* __restrict__ z,
                                                  const float* __restrict__ cb,
                                                  const uint4* __restrict__ cbfrag,
                                                  const float* __restrict__ enorm,
                                                  float* __restrict__ qout,
                                                  float* __restrict__ idxout,
                                                  double* __restrict__ loss_acc,
                                                  uint32* __restrict__ counter,
                                                  float* __restrict__ out0) {
    __shared__ __align__(16) char smem[39968];
    float*       zl   = (float*)smem;              // 128 x STR (34816 B); later ech
    float*       enl  = (float*)(smem + 34816);    // 512 f32
    float*       znl  = (float*)(smem + 36864);    // 128 f32
    ushort16_t*  cand = (ushort16_t*)(smem + 37376); // 128 x 2 x RCAP u16 = 2048 B
    int*         sfin = (int*)(smem + 39424);      // 128
    double*      sred = (double*)(smem + 39936);   // 4

    const int bi    = blockIdx.x;                  // 1024
    const int b     = bi >> 5;
    const int tbase = (bi & 31) * 128;
    const int tid   = threadIdx.x;
    const size_t zoff = (size_t)b * (ND * NT) + tbase;

    // ---- stage z (verified transpose) ----
#pragma unroll
    for (int j = 0; j < 8; ++j) {
        const int qq = j * 256 + tid;
        const int i4 = qq & 31, d = qq >> 5;
        const float4 v = *(const float4*)(z + zoff + (size_t)d * NT + i4 * 4);
        const float vv[4] = {v.x, v.y, v.z, v.w};
#pragma unroll
        for (int c = 0; c < 4; ++c) {
            const int r = i4 * 4 + c;
            zl[PERM(r) * STR + d] = vv[c];
        }
    }
    for (int k = tid; k < NK; k += 256) enl[k] = enorm[k];
    __syncthreads();

    // ---- znorm (verified numpy pairwise, tid<128) ----
    if (tid < 128) {
        const int r = tid;
        const float4* zr4 = (const float4*)&zl[PERM(r) * STR];
        float x[64];
#pragma unroll
        for (int wq = 0; wq < 16; ++wq) {
            const float4 t4 = zr4[wq];
            x[4*wq] = t4.x; x[4*wq+1] = t4.y; x[4*wq+2] = t4.z; x[4*wq+3] = t4.w;
        }
        float r8[8];
#pragma unroll
        for (int jj = 0; jj < 8; ++jj) {
            float s = __fmul_rn(x[jj], x[jj]);
#pragma unroll
            for (int ii = 1; ii < 8; ++ii)
                s = __fadd_rn(s, __fmul_rn(x[8*ii+jj], x[8*ii+jj]));
            r8[jj] = s;
        }
        znl[r] = __fadd_rn(__fadd_rn(__fadd_rn(r8[0],r8[1]), __fadd_rn(r8[2],r8[3])),
                           __fadd_rn(__fadd_rn(r8[4],r8[5]), __fadd_rn(r8[6],r8[7])));
    }

    // ---- B-frags (verified: z rows bf16 hi/lo, same slot->d rule as prep) ----
    const int L    = tid & 63;
    const int w    = tid >> 6;
    const int h    = L >> 5;
    const int rowl = w * 32 + (L & 31);
    short8 bhf[4], blf[4];
    {
        const float* zrow = &zl[PERM(rowl) * STR];
#pragma unroll
        for (int s = 0; s < 4; ++s) {
            const int d0 = s * 16 + h * 8;
            const float4 pa = *(const float4*)(zrow + d0);
            const float4 pb = *(const float4*)(zrow + d0 + 4);
            const float f[8] = {pa.x, pa.y, pa.z, pa.w, pb.x, pb.y, pb.z, pb.w};
            uint32 hw[4], lw[4];
#pragma unroll
            for (int i = 0; i < 4; ++i) {
                const ushort16_t h0 = bf16rne(f[2*i]);
                const ushort16_t h1 = bf16rne(f[2*i+1]);
                const ushort16_t l0 = bf16rne(f[2*i]   - bf16tof(h0));
                const ushort16_t l1 = bf16rne(f[2*i+1] - bf16tof(h1));
                hw[i] = (uint32)h0 | ((uint32)h1 << 16);
                lw[i] = (uint32)l0 | ((uint32)l1 << 16);
            }
            union { uint4 u; short8 s8; } uh, ul;
            uh.u = make_uint4(hw[0],hw[1],hw[2],hw[3]);
            ul.u = make_uint4(lw[0],lw[1],lw[2],lw[3]);
            bhf[s] = uh.s8; blf[s] = ul.s8;
        }
    }
    __syncthreads();

    const int h4 = h * 4;

    // ---- ONE-pass screen: packed top-3, branchless, no barriers ----
    uint32 p1 = 0u, p2 = 0u, p3 = 0u;   // sorted desc; 0 acts as -inf
#pragma unroll 2
    for (int c = 0; c < 16; ++c) {
        uint4 B[8];
#pragma unroll
        for (int p = 0; p < 8; ++p) B[p] = cbfrag[(size_t)((c * 8 + p) * 64) + L];
        f32x16 acc;
#pragma unroll
        for (int r = 0; r < 16; ++r) acc[r] = 0.0f;
#pragma unroll
        for (int s = 0; s < 4; ++s) {
            union { uint4 u; short8 s8; } ah, al;
            ah.u = B[s * 2 + 0];
            al.u = B[s * 2 + 1];
            acc = __builtin_amdgcn_mfma_f32_32x32x16_bf16(ah.s8, bhf[s], acc, 0, 0, 0);
            acc = __builtin_amdgcn_mfma_f32_32x32x16_bf16(al.s8, bhf[s], acc, 0, 0, 0);
            acc = __builtin_amdgcn_mfma_f32_32x32x16_bf16(ah.s8, blf[s], acc, 0, 0, 0);
        }
#pragma unroll
        for (int r = 0; r < 16; ++r) {
            const int kc = c * 32 + ((r & 3) + 8 * (r >> 2)) + h4;
            const uint32 pv = (__float_as_uint(fmaxf(acc[r] + 1.0f, 0.0f)) & ~0x1FFu)
                            | (uint32)kc;
            const bool g1 = pv > p1, g2 = pv > p2, g3 = pv > p3;
            p3 = g2 ? p2 : (g3 ? pv : p3);
            p2 = g1 ? p1 : (g2 ? pv : p2);
            p1 = g1 ? pv : p1;
        }
    }

    // ---- cross-half combine + threshold ----
    const uint32 op1 = __shfl_xor(p1, 32);
    const uint32 pkG = (p1 > op1) ? p1 : op1;    // value-ties force rivals below
    const int    kG  = (int)(pkG & 0x1FFu);
    {
        // bm <= true bmax (round-down); thrf = bm - M2 only widens the window
    }
    const float  bm   = __uint_as_float(pkG & ~0x1FFu) - 1.0f;
    const float  thrf = bm - M2;
    const uint32 thrF = __float_as_uint(fmaxf(thrf + 1.0f, 0.0f)) & ~0x1FFu;

    const float* zrow = &zl[PERM(rowl) * STR];
    const float  zn   = znl[rowl];
    const int    iown = (((kG >> 2) & 1) == h);

    int bkf;
    if (__any((int)(p3 >= thrF))) {
        // ---- rare wave: top-3 may be incomplete -> barrier-free collect ----
        int myc = 0, ovf = 0;
        ushort16_t* mylist = cand + (rowl * 2 + h) * RCAP;
#pragma unroll 1
        for (int c = 0; c < 16; ++c) {
            uint4 B[8];
#pragma unroll
            for (int p = 0; p < 8; ++p) B[p] = cbfrag[(size_t)((c * 8 + p) * 64) + L];
            f32x16 acc;
#pragma unroll
            for (int r = 0; r < 16; ++r) acc[r] = 0.0f;
#pragma unroll
            for (int s = 0; s < 4; ++s) {
                union { uint4 u; short8 s8; } ah, al;
                ah.u = B[s * 2 + 0];
                al.u = B[s * 2 + 1];
                acc = __builtin_amdgcn_mfma_f32_32x32x16_bf16(ah.s8, bhf[s], acc, 0, 0, 0);
                acc = __builtin_amdgcn_mfma_f32_32x32x16_bf16(al.s8, bhf[s], acc, 0, 0, 0);
                acc = __builtin_amdgcn_mfma_f32_32x32x16_bf16(ah.s8, blf[s], acc, 0, 0, 0);
            }
#pragma unroll
            for (int r = 0; r < 16; ++r) {
                const int kc = c * 32 + ((r & 3) + 8 * (r >> 2)) + h4;
                const uint32 pv = (__float_as_uint(fmaxf(acc[r] + 1.0f, 0.0f)) & ~0x1FFu)
                                | (uint32)kc;
                if (pv >= thrF && kc != kG) {
                    if (myc < RCAP) mylist[myc++] = (ushort16_t)kc;
                    else ovf = 1;
                }
            }
        }
        const int totr = myc + __shfl_xor(myc, 32);
        const int aovf = ovf | __shfl_xor(ovf, 32);
        if (aovf) {
            float bd = __builtin_inff(); bkf = 0x7FFFFFFF;
            for (int c = 0; c < 16; ++c)
#pragma unroll
                for (int qd = 0; qd < 4; ++qd)
#pragma unroll
                    for (int i = 0; i < 4; ++i) {
                        const int k2c = c * 32 + qd * 8 + h * 4 + i;
                        const float dv = exact_dist(zrow, cb, enl, zn, k2c);
                        if (dv < bd || (dv == bd && k2c < bkf)) { bd = dv; bkf = k2c; }
                    }
            const float obd = __shfl_xor(bd, 32);
            const int   obq = __shfl_xor(bkf, 32);
            if (obd < bd || (obd == bd && obq < bkf)) bkf = obq;
        } else if (totr > 0) {
            float bd = __builtin_inff(); bkf = 0x7FFFFFFF;
            if (iown) { bd = exact_dist(zrow, cb, enl, zn, kG); bkf = kG; }
            for (int i = 0; i < myc; ++i) {
                const int k2c = mylist[i];
                const float dv = exact_dist(zrow, cb, enl, zn, k2c);
                if (dv < bd || (dv == bd && k2c < bkf)) { bd = dv; bkf = k2c; }
            }
            const float obd = __shfl_xor(bd, 32);
            const int   obq = __shfl_xor(bkf, 32);
            if (obd < bd || (obd == bd && obq < bkf)) bkf = obq;
        } else {
            bkf = kG;
        }
    } else {
        // ---- common wave: rivals are already in registers ----
        const int k1 = (int)(p1 & 0x1FFu);
        const int k2 = (int)(p2 & 0x1FFu);
        const int r1v = (!iown) && (p1 >= thrF);   // losing half's best (R11 fix)
        const int r2v = (p2 >= thrF);
        const int nr  = r1v + r2v;
        const int totr = nr + __shfl_xor(nr, 32);
        if (totr > 0) {
            float bd = __builtin_inff(); bkf = 0x7FFFFFFF;
            if (iown) { bd = exact_dist(zrow, cb, enl, zn, kG); bkf = kG; }
            if (r1v) {
                const float dv = exact_dist(zrow, cb, enl, zn, k1);
                if (dv < bd || (dv == bd && k1 < bkf)) { bd = dv; bkf = k1; }
            }
            if (r2v) {
                const float dv = exact_dist(zrow, cb, enl, zn, k2);
                if (dv < bd || (dv == bd && k2 < bkf)) { bd = dv; bkf = k2; }
            }
            const float obd = __shfl_xor(bd, 32);
            const int   obq = __shfl_xor(bkf, 32);
            if (obd < bd || (obd == bd && obq < bkf)) bkf = obq;
        } else {
            bkf = kG;                     // no rival: screen best is proven
        }
    }

    if (h == 0) {
        sfin[rowl] = bkf;
        idxout[(size_t)b * NT + tbase + rowl] = (float)bkf;
    }
    __syncthreads();

    // ---- staged epilogue (R8 verbatim) ----
    float* ech = zl;
#pragma unroll
    for (int j = 0; j < 8; ++j) {
        const int qq  = j * 256 + tid;
        const int row = qq >> 4, d4 = qq & 15;
        const float4 v = *(const float4*)(cb + (size_t)sfin[row] * ND + d4 * 4);
        float* dst = &ech[row * ESTR + d4 * 4];
        *(float2*)(dst)     = make_float2(v.x, v.y);
        *(float2*)(dst + 2) = make_float2(v.z, v.w);
    }
    __syncthreads();

    double lsum = 0.0;
#pragma unroll 4
    for (int j = 0; j < 32; ++j) {
        const int qq = j * 256 + tid;
        const int ir = qq & 127, d = qq >> 7;
        const float zv = z[zoff + (size_t)d * NT + ir];
        const float ev = ech[ir * ESTR + d];
        const float diff = __fsub_rn(ev, zv);              // quantized - zt
        qout[(size_t)b * (ND*NT) + (size_t)d * NT + tbase + ir] = __fadd_rn(zv, diff);
        lsum += (double)diff * (double)diff;
    }
#pragma unroll
    for (int off = 32; off > 0; off >>= 1) lsum += __shfl_down(lsum, off, 64);
    if ((tid & 63) == 0) sred[tid >> 6] = lsum;
    __syncthreads();

    if (tid == 0) {
        const double bsum = (sred[0] + sred[1]) + (sred[2] + sred[3]);
        atomicAdd(loss_acc, bsum);
        __threadfence();
        const uint32 old = atomicAdd(counter, 1u);
        if (old == (uint32)(NGRID - 1)) {
            __threadfence();
            const double tot = *(volatile double*)loss_acc;
            const double m = tot / (double)((size_t)NB * NT * ND);
            out0[0] = (float)(1.25 * m);   // codebook + 0.25*commitment
        }
    }
}

extern "C" void kernel_launch(void* const* d_in, const int* in_sizes, int n_in,
                              void* d_out, int out_size, void* d_ws, size_t ws_size,
                              hipStream_t stream) {
    const float* z  = (const float*)d_in[0];
    const float* cb = (const float*)d_in[1];

    float* out      = (float*)d_out;
    float* loss_out = out;                                  // 1 elem
    float* qout     = out + 1;                              // B*D*T
    float* idxout   = out + 1 + (size_t)NB * ND * NT;       // B*T

    uint4*  cbfrag   = (uint4*)d_ws;
    float*  enorm    = (float*)((char*)d_ws + 139264);      // 2048 B
    double* loss_acc = (double*)((char*)d_ws + 141312);     // 8 B
    uint32* counter  = (uint32*)((char*)d_ws + 141320);     // 4 B

    prep_kernel<<<17, 256, 0, stream>>>(cb, cbfrag, enorm, loss_acc, counter);
    vq_main<<<NGRID, 256, 0, stream>>>(z, cb, cbfrag, enorm, qout, idxout,
                                       loss_acc, counter, loss_out);
}

// Round 7
// 178.924 us; speedup vs baseline: 1.8034x; 1.0476x over previous
//
#include <hip/hip_runtime.h>

#define NB 32
#define ND 64
#define NT 4096
#define NK 512
#define NGRID 1024

typedef __attribute__((ext_vector_type(8))) short short8;
typedef __attribute__((ext_vector_type(16))) float f32x16;
typedef unsigned int uint32;
typedef unsigned short ushort16_t;

#define PERM(r) ((((r) & 7) * 16) + ((r) >> 3))
#define STR 68
#define ESTR 66
// acc-domain margin: bound = emax/2 + 2*eps_dot ~= 1.56e-4 (emax = 64/512^2).
// M2 = 2.5e-4 gives 1.6x safety; packed-quantization (<=6.1e-5) only WIDENS
// collection (round-down superset) and the p3-guard (more fallbacks) - safe.
// 2-way acc split regroups the same 12 partial products: adds ~1e-7, absorbed.
#define M2 2.5e-4f
#define RCAP 4
#define NSLOT 16

__device__ __forceinline__ ushort16_t bf16rne(float f) {
    uint32 u = __float_as_uint(f);
    return (ushort16_t)((u + 0x7FFFu + ((u >> 16) & 1u)) >> 16);
}
__device__ __forceinline__ float bf16tof(ushort16_t h) {
    return __uint_as_float(((uint32)h) << 16);
}

// ---------------------------------------------------------------------------
// prep (verified R6-R8): blocks 0..15 pack cb into MFMA A-frags (bf16 hi/lo);
// block 16: exact numpy-pairwise enorm + zero loss slots/counter.
// ---------------------------------------------------------------------------
__global__ void prep_kernel(const float* __restrict__ cb,
                            uint4* __restrict__ cbfrag,
                            float* __restrict__ enorm,
                            double* __restrict__ loss_acc,
                            uint32* __restrict__ counter) {
    const int bi = blockIdx.x, tid = threadIdx.x;
    if (bi < 16) {
        const int t = bi * 256 + tid;
        const int c = t >> 8, rem = t & 255, s = rem >> 6, L = rem & 63;
        const int kcode = c * 32 + (L & 31);
        const int dbase = s * 16 + ((L >> 5) << 3);
        const float* src = cb + (size_t)kcode * 64 + dbase;
        const float4 pa = *(const float4*)src;
        const float4 pb = *(const float4*)(src + 4);
        const float f[8] = {pa.x, pa.y, pa.z, pa.w, pb.x, pb.y, pb.z, pb.w};
        uint32 hw[4], lw[4];
#pragma unroll
        for (int i = 0; i < 4; ++i) {
            const ushort16_t h0 = bf16rne(f[2*i]);
            const ushort16_t h1 = bf16rne(f[2*i+1]);
            const ushort16_t l0 = bf16rne(f[2*i]   - bf16tof(h0));
            const ushort16_t l1 = bf16rne(f[2*i+1] - bf16tof(h1));
            hw[i] = (uint32)h0 | ((uint32)h1 << 16);
            lw[i] = (uint32)l0 | ((uint32)l1 << 16);
        }
        cbfrag[(size_t)((c*4+s)*2 + 0)*64 + L] = make_uint4(hw[0],hw[1],hw[2],hw[3]);
        cbfrag[(size_t)((c*4+s)*2 + 1)*64 + L] = make_uint4(lw[0],lw[1],lw[2],lw[3]);
    } else {
        if (tid < NSLOT) loss_acc[tid] = 0.0;
        if (tid == 0) *counter = 0u;
        for (int k = tid; k < NK; k += 256) {
            const float* e = cb + (size_t)k * ND;
            float r[8];
#pragma unroll
            for (int j = 0; j < 8; ++j) {
                float s = __fmul_rn(e[j], e[j]);
#pragma unroll
                for (int i = 1; i < 8; ++i)
                    s = __fadd_rn(s, __fmul_rn(e[8*i+j], e[8*i+j]));
                r[j] = s;
            }
            enorm[k] = __fadd_rn(__fadd_rn(__fadd_rn(r[0],r[1]), __fadd_rn(r[2],r[3])),
                                 __fadd_rn(__fadd_rn(r[4],r[5]), __fadd_rn(r[6],r[7])));
        }
    }
}

// exact dist — the R1-R8 verified bit-exact chain
__device__ __forceinline__ float exact_dist(const float* __restrict__ zrow,
                                            const float* __restrict__ cb,
                                            const float* __restrict__ enl,
                                            float zn, int k2) {
    const float4* e4 = (const float4*)(cb + (size_t)k2 * ND);
    float a = 0.0f;
#pragma unroll
    for (int w = 0; w < 16; ++w) {
        const float4 ev = e4[w];
        const float4 zv = *(const float4*)(zrow + 4 * w);
        a = __builtin_fmaf(zv.x, ev.x, a);
        a = __builtin_fmaf(zv.y, ev.y, a);
        a = __builtin_fmaf(zv.z, ev.z, a);
        a = __builtin_fmaf(zv.w, ev.w, a);
    }
    return __fsub_rn(__fadd_rn(zn, enl[k2]), __fmul_rn(2.0f, a));
}

// ---------------------------------------------------------------------------
// R16 main: R15's one-pass packed-top-3 screen with (A) 2-way accumulator
// split (MFMA dep-chain 12 -> 8, merge adds at chunk end), (B) float4-
// vectorized loss epilogue (8 wide mem iters instead of 32 scalar), and
// (C) loss atomics spread over 16 slots. Rival logic, exact chain,
// ech staging: R15-verbatim.
// ---------------------------------------------------------------------------
__global__ __launch_bounds__(256, 3) void vq_main(const float* __restrict__ z,
                                                  const float* __restrict__ cb,
                                                  const uint4* __restrict__ cbfrag,
                                                  const float* __restrict__ enorm,
                                                  float* __restrict__ qout,
                                                  float* __restrict__ idxout,
                                                  double* __restrict__ loss_acc,
                                                  uint32* __restrict__ counter,
                                                  float* __restrict__ out0) {
    __shared__ __align__(16) char smem[39968];
    float*       zl   = (float*)smem;              // 128 x STR (34816 B); later ech
    float*       enl  = (float*)(smem + 34816);    // 512 f32
    float*       znl  = (float*)(smem + 36864);    // 128 f32
    ushort16_t*  cand = (ushort16_t*)(smem + 37376); // 128 x 2 x RCAP u16 = 2048 B
    int*         sfin = (int*)(smem + 39424);      // 128
    double*      sred = (double*)(smem + 39936);   // 4

    const int bi    = blockIdx.x;                  // 1024
    const int b     = bi >> 5;
    const int tbase = (bi & 31) * 128;
    const int tid   = threadIdx.x;
    const size_t zoff = (size_t)b * (ND * NT) + tbase;

    // ---- stage z (verified transpose) ----
#pragma unroll
    for (int j = 0; j < 8; ++j) {
        const int qq = j * 256 + tid;
        const int i4 = qq & 31, d = qq >> 5;
        const float4 v = *(const float4*)(z + zoff + (size_t)d * NT + i4 * 4);
        const float vv[4] = {v.x, v.y, v.z, v.w};
#pragma unroll
        for (int c = 0; c < 4; ++c) {
            const int r = i4 * 4 + c;
            zl[PERM(r) * STR + d] = vv[c];
        }
    }
    for (int k = tid; k < NK; k += 256) enl[k] = enorm[k];
    __syncthreads();

    // ---- znorm (verified numpy pairwise, tid<128) ----
    if (tid < 128) {
        const int r = tid;
        const float4* zr4 = (const float4*)&zl[PERM(r) * STR];
        float x[64];
#pragma unroll
        for (int wq = 0; wq < 16; ++wq) {
            const float4 t4 = zr4[wq];
            x[4*wq] = t4.x; x[4*wq+1] = t4.y; x[4*wq+2] = t4.z; x[4*wq+3] = t4.w;
        }
        float r8[8];
#pragma unroll
        for (int jj = 0; jj < 8; ++jj) {
            float s = __fmul_rn(x[jj], x[jj]);
#pragma unroll
            for (int ii = 1; ii < 8; ++ii)
                s = __fadd_rn(s, __fmul_rn(x[8*ii+jj], x[8*ii+jj]));
            r8[jj] = s;
        }
        znl[r] = __fadd_rn(__fadd_rn(__fadd_rn(r8[0],r8[1]), __fadd_rn(r8[2],r8[3])),
                           __fadd_rn(__fadd_rn(r8[4],r8[5]), __fadd_rn(r8[6],r8[7])));
    }

    // ---- B-frags (verified: z rows bf16 hi/lo, same slot->d rule as prep) ----
    const int L    = tid & 63;
    const int w    = tid >> 6;
    const int h    = L >> 5;
    const int rowl = w * 32 + (L & 31);
    short8 bhf[4], blf[4];
    {
        const float* zrow = &zl[PERM(rowl) * STR];
#pragma unroll
        for (int s = 0; s < 4; ++s) {
            const int d0 = s * 16 + h * 8;
            const float4 pa = *(const float4*)(zrow + d0);
            const float4 pb = *(const float4*)(zrow + d0 + 4);
            const float f[8] = {pa.x, pa.y, pa.z, pa.w, pb.x, pb.y, pb.z, pb.w};
            uint32 hw[4], lw[4];
#pragma unroll
            for (int i = 0; i < 4; ++i) {
                const ushort16_t h0 = bf16rne(f[2*i]);
                const ushort16_t h1 = bf16rne(f[2*i+1]);
                const ushort16_t l0 = bf16rne(f[2*i]   - bf16tof(h0));
                const ushort16_t l1 = bf16rne(f[2*i+1] - bf16tof(h1));
                hw[i] = (uint32)h0 | ((uint32)h1 << 16);
                lw[i] = (uint32)l0 | ((uint32)l1 << 16);
            }
            union { uint4 u; short8 s8; } uh, ul;
            uh.u = make_uint4(hw[0],hw[1],hw[2],hw[3]);
            ul.u = make_uint4(lw[0],lw[1],lw[2],lw[3]);
            bhf[s] = uh.s8; blf[s] = ul.s8;
        }
    }
    __syncthreads();

    const int h4 = h * 4;

    // ---- ONE-pass screen: packed top-3, branchless, no barriers ----
    uint32 p1 = 0u, p2 = 0u, p3 = 0u;   // sorted desc; 0 acts as -inf
#pragma unroll 2
    for (int c = 0; c < 16; ++c) {
        uint4 B[8];
#pragma unroll
        for (int p = 0; p < 8; ++p) B[p] = cbfrag[(size_t)((c * 8 + p) * 64) + L];
        f32x16 acc0, acc1;
#pragma unroll
        for (int r = 0; r < 16; ++r) { acc0[r] = 0.0f; acc1[r] = 0.0f; }
#pragma unroll
        for (int s = 0; s < 4; ++s) {
            union { uint4 u; short8 s8; } ah, al;
            ah.u = B[s * 2 + 0];
            al.u = B[s * 2 + 1];
            acc0 = __builtin_amdgcn_mfma_f32_32x32x16_bf16(ah.s8, bhf[s], acc0, 0, 0, 0);
            acc0 = __builtin_amdgcn_mfma_f32_32x32x16_bf16(al.s8, bhf[s], acc0, 0, 0, 0);
            acc1 = __builtin_amdgcn_mfma_f32_32x32x16_bf16(ah.s8, blf[s], acc1, 0, 0, 0);
        }
#pragma unroll
        for (int r = 0; r < 16; ++r) {
            const int kc = c * 32 + ((r & 3) + 8 * (r >> 2)) + h4;
            const float a = acc0[r] + acc1[r];
            const uint32 pv = (__float_as_uint(fmaxf(a + 1.0f, 0.0f)) & ~0x1FFu)
                            | (uint32)kc;
            const bool g1 = pv > p1, g2 = pv > p2, g3 = pv > p3;
            p3 = g2 ? p2 : (g3 ? pv : p3);
            p2 = g1 ? p1 : (g2 ? pv : p2);
            p1 = g1 ? pv : p1;
        }
    }

    // ---- cross-half combine + threshold ----
    const uint32 op1 = __shfl_xor(p1, 32);
    const uint32 pkG = (p1 > op1) ? p1 : op1;    // value-ties force rivals below
    const int    kG  = (int)(pkG & 0x1FFu);
    const float  bm   = __uint_as_float(pkG & ~0x1FFu) - 1.0f;
    const float  thrf = bm - M2;
    const uint32 thrF = __float_as_uint(fmaxf(thrf + 1.0f, 0.0f)) & ~0x1FFu;

    const float* zrow = &zl[PERM(rowl) * STR];
    const float  zn   = znl[rowl];
    const int    iown = (((kG >> 2) & 1) == h);

    int bkf;
    if (__any((int)(p3 >= thrF))) {
        // ---- rare wave: top-3 may be incomplete -> barrier-free collect ----
        int myc = 0, ovf = 0;
        ushort16_t* mylist = cand + (rowl * 2 + h) * RCAP;
#pragma unroll 1
        for (int c = 0; c < 16; ++c) {
            uint4 B[8];
#pragma unroll
            for (int p = 0; p < 8; ++p) B[p] = cbfrag[(size_t)((c * 8 + p) * 64) + L];
            f32x16 acc0, acc1;
#pragma unroll
            for (int r = 0; r < 16; ++r) { acc0[r] = 0.0f; acc1[r] = 0.0f; }
#pragma unroll
            for (int s = 0; s < 4; ++s) {
                union { uint4 u; short8 s8; } ah, al;
                ah.u = B[s * 2 + 0];
                al.u = B[s * 2 + 1];
                acc0 = __builtin_amdgcn_mfma_f32_32x32x16_bf16(ah.s8, bhf[s], acc0, 0, 0, 0);
                acc0 = __builtin_amdgcn_mfma_f32_32x32x16_bf16(al.s8, bhf[s], acc0, 0, 0, 0);
                acc1 = __builtin_amdgcn_mfma_f32_32x32x16_bf16(ah.s8, blf[s], acc1, 0, 0, 0);
            }
#pragma unroll
            for (int r = 0; r < 16; ++r) {
                const int kc = c * 32 + ((r & 3) + 8 * (r >> 2)) + h4;
                const float a = acc0[r] + acc1[r];
                const uint32 pv = (__float_as_uint(fmaxf(a + 1.0f, 0.0f)) & ~0x1FFu)
                                | (uint32)kc;
                if (pv >= thrF && kc != kG) {
                    if (myc < RCAP) mylist[myc++] = (ushort16_t)kc;
                    else ovf = 1;
                }
            }
        }
        const int totr = myc + __shfl_xor(myc, 32);
        const int aovf = ovf | __shfl_xor(ovf, 32);
        if (aovf) {
            float bd = __builtin_inff(); bkf = 0x7FFFFFFF;
            for (int c = 0; c < 16; ++c)
#pragma unroll
                for (int qd = 0; qd < 4; ++qd)
#pragma unroll
                    for (int i = 0; i < 4; ++i) {
                        const int k2c = c * 32 + qd * 8 + h * 4 + i;
                        const float dv = exact_dist(zrow, cb, enl, zn, k2c);
                        if (dv < bd || (dv == bd && k2c < bkf)) { bd = dv; bkf = k2c; }
                    }
            const float obd = __shfl_xor(bd, 32);
            const int   obq = __shfl_xor(bkf, 32);
            if (obd < bd || (obd == bd && obq < bkf)) bkf = obq;
        } else if (totr > 0) {
            float bd = __builtin_inff(); bkf = 0x7FFFFFFF;
            if (iown) { bd = exact_dist(zrow, cb, enl, zn, kG); bkf = kG; }
            for (int i = 0; i < myc; ++i) {
                const int k2c = mylist[i];
                const float dv = exact_dist(zrow, cb, enl, zn, k2c);
                if (dv < bd || (dv == bd && k2c < bkf)) { bd = dv; bkf = k2c; }
            }
            const float obd = __shfl_xor(bd, 32);
            const int   obq = __shfl_xor(bkf, 32);
            if (obd < bd || (obd == bd && obq < bkf)) bkf = obq;
        } else {
            bkf = kG;
        }
    } else {
        // ---- common wave: rivals are already in registers ----
        const int k1 = (int)(p1 & 0x1FFu);
        const int k2 = (int)(p2 & 0x1FFu);
        const int r1v = (!iown) && (p1 >= thrF);   // losing half's best (R11 fix)
        const int r2v = (p2 >= thrF);
        const int nr  = r1v + r2v;
        const int totr = nr + __shfl_xor(nr, 32);
        if (totr > 0) {
            float bd = __builtin_inff(); bkf = 0x7FFFFFFF;
            if (iown) { bd = exact_dist(zrow, cb, enl, zn, kG); bkf = kG; }
            if (r1v) {
                const float dv = exact_dist(zrow, cb, enl, zn, k1);
                if (dv < bd || (dv == bd && k1 < bkf)) { bd = dv; bkf = k1; }
            }
            if (r2v) {
                const float dv = exact_dist(zrow, cb, enl, zn, k2);
                if (dv < bd || (dv == bd && k2 < bkf)) { bd = dv; bkf = k2; }
            }
            const float obd = __shfl_xor(bd, 32);
            const int   obq = __shfl_xor(bkf, 32);
            if (obd < bd || (obd == bd && obq < bkf)) bkf = obq;
        } else {
            bkf = kG;                     // no rival: screen best is proven
        }
    }

    if (h == 0) {
        sfin[rowl] = bkf;
        idxout[(size_t)b * NT + tbase + rowl] = (float)bkf;
    }
    __syncthreads();

    // ---- staged epilogue: ech build (R8 verbatim) ----
    float* ech = zl;
#pragma unroll
    for (int j = 0; j < 8; ++j) {
        const int qq  = j * 256 + tid;
        const int row = qq >> 4, d4 = qq & 15;
        const float4 v = *(const float4*)(cb + (size_t)sfin[row] * ND + d4 * 4);
        float* dst = &ech[row * ESTR + d4 * 4];
        *(float2*)(dst)     = make_float2(v.x, v.y);
        *(float2*)(dst + 2) = make_float2(v.z, v.w);
    }
    __syncthreads();

    // ---- loss + qout: float4-vectorized (same per-element arithmetic) ----
    double lsum = 0.0;
#pragma unroll 4
    for (int j = 0; j < 8; ++j) {
        const int qq  = j * 256 + tid;
        const int ir0 = (qq & 31) * 4, d = qq >> 5;
        const float4 zv4 = *(const float4*)(z + zoff + (size_t)d * NT + ir0);
        const float zv[4] = {zv4.x, zv4.y, zv4.z, zv4.w};
        float qo[4];
#pragma unroll
        for (int m = 0; m < 4; ++m) {
            const float ev = ech[(ir0 + m) * ESTR + d];
            const float diff = __fsub_rn(ev, zv[m]);       // quantized - zt
            qo[m] = __fadd_rn(zv[m], diff);
            lsum += (double)diff * (double)diff;
        }
        *(float4*)(qout + (size_t)b * (ND*NT) + (size_t)d * NT + tbase + ir0) =
            make_float4(qo[0], qo[1], qo[2], qo[3]);
    }
#pragma unroll
    for (int off = 32; off > 0; off >>= 1) lsum += __shfl_down(lsum, off, 64);
    if ((tid & 63) == 0) sred[tid >> 6] = lsum;
    __syncthreads();

    if (tid == 0) {
        const double bsum = (sred[0] + sred[1]) + (sred[2] + sred[3]);
        atomicAdd(loss_acc + (bi & (NSLOT - 1)), bsum);
        __threadfence();
        const uint32 old = atomicAdd(counter, 1u);
        if (old == (uint32)(NGRID - 1)) {
            __threadfence();
            double tot = 0.0;
            for (int i = 0; i < NSLOT; ++i)
                tot += ((volatile double*)loss_acc)[i];
            const double m = tot / (double)((size_t)NB * NT * ND);
            out0[0] = (float)(1.25 * m);   // codebook + 0.25*commitment
        }
    }
}

extern "C" void kernel_launch(void* const* d_in, const int* in_sizes, int n_in,
                              void* d_out, int out_size, void* d_ws, size_t ws_size,
                              hipStream_t stream) {
    const float* z  = (const float*)d_in[0];
    const float* cb = (const float*)d_in[1];

    float* out      = (float*)d_out;
    float* loss_out = out;                                  // 1 elem
    float* qout     = out + 1;                              // B*D*T
    float* idxout   = out + 1 + (size_t)NB * ND * NT;       // B*T

    uint4*  cbfrag   = (uint4*)d_ws;
    float*  enorm    = (float*)((char*)d_ws + 139264);      // 2048 B
    double* loss_acc = (double*)((char*)d_ws + 141312);     // 16 x 8 B
    uint32* counter  = (uint32*)((char*)d_ws + 141440);     // 4 B

    prep_kernel<<<17, 256, 0, stream>>>(cb, cbfrag, enorm, loss_acc, counter);
    vq_main<<<NGRID, 256, 0, stream>>>(z, cb, cbfrag, enorm, qout, idxout,
                                       loss_acc, counter, loss_out);
}